// Round 5
// baseline (279.903 us; speedup 1.0000x reference)
//
#include <hip/hip_runtime.h>

typedef unsigned short u16;
typedef unsigned int uint32;
typedef __bf16 bf16x8 __attribute__((ext_vector_type(8)));
typedef float f32x4 __attribute__((ext_vector_type(4)));

static constexpr int Gg = 64;
static constexpr int Nn = 2048;
static constexpr int Ee = 16384;
static constexpr int GN = Gg * Nn;   // 131072
static constexpr int GE = Gg * Ee;   // 1048576

__device__ __forceinline__ u16 f2u(float f) {  // round-to-nearest-even bf16
    uint32 i = __float_as_uint(f);
    uint32 r = (i + 0x7FFFu + ((i >> 16) & 1u)) >> 16;
    return (u16)r;
}
__device__ __forceinline__ float lo16f(uint32 v) { return __uint_as_float(v << 16); }
__device__ __forceinline__ float hi16f(uint32 v) { return __uint_as_float(v & 0xffff0000u); }

// ---------------- setup kernels ----------------

// per-graph LDS histogram of (dst, src-quarter) -> packed per-quarter counts,
// dis, invdeg (no global atomics). Quarter = (src local) >> 9: the src-quarter
// ordering makes k_propx's gather footprint 2.1MB per phase (fits 4MB L2/XCD;
// measured 8.4MB footprint caused FETCH 166MB vs 77MB compulsory).
__global__ __launch_bounds__(1024) void k_hist(const int* __restrict__ ei,
                                               uint32* __restrict__ degq01, uint32* __restrict__ degq23,
                                               float* __restrict__ dis, float* __restrict__ invdeg) {
    int g = blockIdx.x, t = threadIdx.x;
    __shared__ int h[8192];            // [q][2048]
    #pragma unroll
    for (int k = 0; k < 8; ++k) h[k * 1024 + t] = 0;
    __syncthreads();
    #pragma unroll
    for (int k = 0; k < 16; ++k) {
        int e = g * Ee + k * 1024 + t;
        int s = ei[e] & (Nn - 1);
        int d = ei[GE + e] & (Nn - 1);
        atomicAdd(&h[(s >> 9) * 2048 + d], 1);
    }
    __syncthreads();
    #pragma unroll
    for (int k = 0; k < 2; ++k) {
        int i = k * 1024 + t;
        int c0 = h[i], c1 = h[2048 + i], c2 = h[4096 + i], c3 = h[6144 + i];
        int c = c0 + c1 + c2 + c3;
        degq01[(g << 11) + i] = (uint32)c0 | ((uint32)c1 << 16);
        degq23[(g << 11) + i] = (uint32)c2 | ((uint32)c3 << 16);
        float dd = 1.0f + (float)c;
        dis[(g << 11) + i] = rsqrtf(dd);
        invdeg[(g << 11) + i] = 1.0f / dd;
    }
}

// per-group (8 graphs) exclusive scan over nodes -> pos_pn[p][i] (absolute, base p<<17)
__global__ void k_scan_p(const uint32* __restrict__ degq01, const uint32* __restrict__ degq23,
                         int* __restrict__ pos_pn) {
    int p = blockIdx.x, t = threadIdx.x;   // 1024 threads, 2 nodes each
    int i0 = 2 * t, i1 = 2 * t + 1;
    int c0 = 0, c1 = 0;
    #pragma unroll
    for (int g8 = 0; g8 < 8; ++g8) {
        int g = p * 8 + g8;
        uint32 a01 = degq01[(g << 11) + i0], a23 = degq23[(g << 11) + i0];
        c0 += (int)((a01 & 0xffff) + (a01 >> 16) + (a23 & 0xffff) + (a23 >> 16));
        uint32 b01 = degq01[(g << 11) + i1], b23 = degq23[(g << 11) + i1];
        c1 += (int)((b01 & 0xffff) + (b01 >> 16) + (b23 & 0xffff) + (b23 >> 16));
    }
    __shared__ int ps[1024];
    ps[t] = c0 + c1; __syncthreads();
    for (int off = 1; off < 1024; off <<= 1) {
        int v = (t >= off) ? ps[t - off] : 0;
        __syncthreads();
        ps[t] += v;
        __syncthreads();
    }
    int base = (p << 17) + ps[t] - (c0 + c1);
    pos_pn[p * 2049 + i0] = base;
    pos_pn[p * 2049 + i1] = base + c0;
    if (t == 1023) pos_pn[p * 2049 + 2048] = (p + 1) << 17;
}

// deterministic per-(g,i,q) starts, QUARTER-MAJOR then graph within the (p,i)
// bucket: bucket = [q0: g0..g7][q1: g0..g7][q2..][q3..]
__global__ void k_start(const uint32* __restrict__ degq01, const uint32* __restrict__ degq23,
                        const int* __restrict__ pos_pn, int* __restrict__ gstartq) {
    int i = blockIdx.x * 256 + threadIdx.x;   // node 0..2047
    #pragma unroll
    for (int p = 0; p < 8; ++p) {
        uint32 w01[8], w23[8];
        #pragma unroll
        for (int g8 = 0; g8 < 8; ++g8) {
            int g = p * 8 + g8;
            w01[g8] = degq01[(g << 11) + i];
            w23[g8] = degq23[(g << 11) + i];
        }
        int run = pos_pn[p * 2049 + i];
        #pragma unroll
        for (int q = 0; q < 4; ++q) {
            #pragma unroll
            for (int g8 = 0; g8 < 8; ++g8) {
                int g = p * 8 + g8;
                gstartq[(((g << 11) + i) << 2) + q] = run;
                int cnt = (q == 0) ? (int)(w01[g8] & 0xffff) :
                          (q == 1) ? (int)(w01[g8] >> 16) :
                          (q == 2) ? (int)(w23[g8] & 0xffff) :
                                     (int)(w23[g8] >> 16);
                run += cnt;
            }
        }
    }
}

// per-graph scatter with 4-way (quarter) LDS cursors (no global atomics)
__global__ __launch_bounds__(1024) void k_scatter(const int* __restrict__ ei, const float* __restrict__ dis,
                                                  const int* __restrict__ gstartq, int2* __restrict__ nme) {
    int g = blockIdx.x, t = threadIdx.x;
    __shared__ int curs[8192];         // [q][2048]
    #pragma unroll
    for (int k = 0; k < 2; ++k) {
        int d = k * 1024 + t;
        int4 gs = *(const int4*)&gstartq[((g << 11) + d) << 2];
        curs[d] = gs.x; curs[2048 + d] = gs.y; curs[4096 + d] = gs.z; curs[6144 + d] = gs.w;
    }
    __syncthreads();
    #pragma unroll
    for (int k = 0; k < 16; ++k) {
        int e = g * Ee + k * 1024 + t;
        int s = ei[e];          // src gid
        int d = ei[GE + e];     // dst gid
        int q = (s & (Nn - 1)) >> 9;
        int p = atomicAdd(&curs[q * 2048 + (d & (Nn - 1))], 1);
        nme[p] = make_int2(s, __float_as_int(dis[s] * dis[d]));
    }
}

// pack bottom half of Wm into MFMA fragment order (A-operand of transposed GEMM):
// Wtp[((ks*8+ct)*64 + l)*8 + j] = bf16(Wm[(128 + ks*32+lq*8+j)*128 + ct*16+lm]), l=lq*16+lm
__global__ void k_trans(const float* __restrict__ Wm, u16* __restrict__ Wtp) {
    int tid = blockIdx.x * 256 + threadIdx.x;   // 16384
    int j = tid & 7, l = (tid >> 3) & 63, kc = tid >> 9;
    int ks = kc >> 3, ct = kc & 7, lm = l & 15, lq = l >> 4;
    int f = ks * 32 + lq * 8 + j, c = ct * 16 + lm;
    Wtp[tid] = f2u(Wm[(128 + f) * 128 + c]);
}

// A[g] = (ce @ Wm_top) + bm, ce = (x[center]*invdeg + incident edges) @ W1 + b1
__global__ void k_A(const float* __restrict__ x, const int* __restrict__ center,
                    const float* __restrict__ invdeg, const int* __restrict__ gstartq,
                    const uint32* __restrict__ degq01, const uint32* __restrict__ degq23,
                    const int2* __restrict__ nme,
                    const float* __restrict__ W1, const float* __restrict__ b1,
                    const float* __restrict__ Wm, const float* __restrict__ bm,
                    float* __restrict__ A) {
    int g = blockIdx.x, t = threadIdx.x;   // 128 threads
    __shared__ float cepre[128], ce[128];
    int cg = (g << 11) + center[g];
    float v = x[cg * 128 + t] * invdeg[cg];
    uint32 a01 = degq01[cg], a23 = degq23[cg];
    int cnt[4] = { (int)(a01 & 0xffff), (int)(a01 >> 16), (int)(a23 & 0xffff), (int)(a23 >> 16) };
    int4 gs = *(const int4*)&gstartq[cg << 2];
    int st[4] = { gs.x, gs.y, gs.z, gs.w };
    #pragma unroll
    for (int q = 0; q < 4; ++q) {           // usually empty (center has no in-edges)
        for (int e = st[q]; e < st[q] + cnt[q]; ++e) {
            int2 m = nme[e];
            v += __int_as_float(m.y) * x[m.x * 128 + t];
        }
    }
    cepre[t] = v; __syncthreads();
    float a = b1[t];
    #pragma unroll 8
    for (int f = 0; f < 128; ++f) a += cepre[f] * W1[f * 128 + t];
    ce[t] = a; __syncthreads();
    float o = bm[t];
    #pragma unroll 8
    for (int h = 0; h < 128; ++h) o += ce[h] * Wm[h * 128 + t];
    A[g * 128 + t] = o;
}

// ---------------- mask + y GEMM (MFMA, TRANSPOSED), packed xy ----------------
// xy row (256 u16): group k (u16[4k..4k+4)) = { y[2k], y[2k+1], x[2k], x[2k+1] } bf16
// D = W^T x^T via mfma(A=Wtp-frag, B=x-frag); each lane gets 4 consecutive
// channels of one x-row per ct = exactly one 16B packed chunk (no LDS transpose,
// one store completes each 64B line segment).
__global__ __launch_bounds__(256) void k_masky(const float* __restrict__ x,
                                               const u16* __restrict__ Wtp,
                                               const float* __restrict__ A,
                                               u16* __restrict__ xy) {
    __shared__ float sA[128];
    int t = threadIdx.x;
    int tile = blockIdx.x;            // 0..2047, 64 rows each
    int g = tile >> 5;
    if (t < 128) sA[t] = A[g * 128 + t];
    __syncthreads();

    int w = t >> 6, l = t & 63;
    int lm = l & 15, lq = l >> 4;
    int row = tile * 64 + w * 16 + lm;      // this lane's x-row
    const float* xrow = x + row * 128;
    const bf16x8* Ap = (const bf16x8*)Wtp;

    float4 xf[8];
    #pragma unroll
    for (int ks = 0; ks < 4; ++ks) {
        xf[2 * ks]     = *(const float4*)(xrow + ks * 32 + lq * 8);
        xf[2 * ks + 1] = *(const float4*)(xrow + ks * 32 + lq * 8 + 4);
    }
    union { u16 u[8]; bf16x8 v; } bf[4];
    #pragma unroll
    for (int ks = 0; ks < 4; ++ks) {
        float4 x0 = xf[2 * ks], x1 = xf[2 * ks + 1];
        bf[ks].u[0] = f2u(x0.x); bf[ks].u[1] = f2u(x0.y);
        bf[ks].u[2] = f2u(x0.z); bf[ks].u[3] = f2u(x0.w);
        bf[ks].u[4] = f2u(x1.x); bf[ks].u[5] = f2u(x1.y);
        bf[ks].u[6] = f2u(x1.z); bf[ks].u[7] = f2u(x1.w);
    }

    f32x4 acc[8] = {};
    #pragma unroll
    for (int ks = 0; ks < 4; ++ks) {
        #pragma unroll
        for (int ct = 0; ct < 8; ++ct) {
            bf16x8 a = Ap[(ks * 8 + ct) * 64 + l];
            acc[ct] = __builtin_amdgcn_mfma_f32_16x16x32_bf16(a, bf[ks].v, acc[ct], 0, 0, 0);
        }
    }

    u16* orow = xy + row * 256;
    #pragma unroll
    for (int ct = 0; ct < 8; ++ct) {
        int ch = ct * 16 + lq * 4;
        float4 xv = *(const float4*)(xrow + ch);   // L1-hot
        float y0 = fmaxf(acc[ct][0] + sA[ch + 0], 0.f) * xv.x;
        float y1 = fmaxf(acc[ct][1] + sA[ch + 1], 0.f) * xv.y;
        float y2 = fmaxf(acc[ct][2] + sA[ch + 2], 0.f) * xv.z;
        float y3 = fmaxf(acc[ct][3] + sA[ch + 3], 0.f) * xv.w;
        uint4 q;
        q.x = (uint32)f2u(y0)   | ((uint32)f2u(y1)   << 16);
        q.y = (uint32)f2u(xv.x) | ((uint32)f2u(xv.y) << 16);
        q.z = (uint32)f2u(y2)   | ((uint32)f2u(y3)   << 16);
        q.w = (uint32)f2u(xv.z) | ((uint32)f2u(xv.w) << 16);
        *(uint4*)(orow + ct * 32 + lq * 8) = q;
    }
}

// ---------------- propagation: half-wave row mapping, 16 edges in flight ----------------
// Buckets are src-quarter-major ordered: each 16-edge iteration stays within a
// ~2.1MB xy footprint that fits the XCD's 4MB L2 (p = b&7 aligns p with XCD).
#define ACC8(v, cf)                                                     \
    aY0 += (cf) * lo16f((v).x); aY1 += (cf) * hi16f((v).x);             \
    aX0 += (cf) * lo16f((v).y); aX1 += (cf) * hi16f((v).y);             \
    aY2 += (cf) * lo16f((v).z); aY3 += (cf) * hi16f((v).z);             \
    aX2 += (cf) * lo16f((v).w); aX3 += (cf) * hi16f((v).w);

__global__ __launch_bounds__(256) void k_propx(const u16* __restrict__ xy,
                                               const float* __restrict__ invdeg,
                                               const int* __restrict__ pos_pn,
                                               const int2* __restrict__ nme,
                                               float* __restrict__ zp) {
    int b = blockIdx.x;
    int p = b & 7, c = b >> 3;
    int t = threadIdx.x, w = t >> 6, l = t & 63;
    int half = l >> 5, cl = l & 31;
    int i = c * 4 + w;
    float aY0 = 0.f, aY1 = 0.f, aY2 = 0.f, aY3 = 0.f;
    float aX0 = 0.f, aX1 = 0.f, aX2 = 0.f, aX3 = 0.f;

    #pragma unroll
    for (int k = 0; k < 4; ++k) {
        int gid = ((p * 8 + 2 * k + half) << 11) + i;
        float cf = invdeg[gid];
        uint4 v = *(const uint4*)(xy + gid * 256 + cl * 8);
        ACC8(v, cf)
    }

    int j = pos_pn[p * 2049 + i], jend = pos_pn[p * 2049 + i + 1];
    for (; j + 15 < jend; j += 16) {
        int2 m0 = nme[j + half];
        int2 m1 = nme[j + 2 + half];
        int2 m2 = nme[j + 4 + half];
        int2 m3 = nme[j + 6 + half];
        int2 m4 = nme[j + 8 + half];
        int2 m5 = nme[j + 10 + half];
        int2 m6 = nme[j + 12 + half];
        int2 m7 = nme[j + 14 + half];
        uint4 v0 = *(const uint4*)(xy + m0.x * 256 + cl * 8);
        uint4 v1 = *(const uint4*)(xy + m1.x * 256 + cl * 8);
        uint4 v2 = *(const uint4*)(xy + m2.x * 256 + cl * 8);
        uint4 v3 = *(const uint4*)(xy + m3.x * 256 + cl * 8);
        uint4 v4 = *(const uint4*)(xy + m4.x * 256 + cl * 8);
        uint4 v5 = *(const uint4*)(xy + m5.x * 256 + cl * 8);
        uint4 v6 = *(const uint4*)(xy + m6.x * 256 + cl * 8);
        uint4 v7 = *(const uint4*)(xy + m7.x * 256 + cl * 8);
        float c0 = __int_as_float(m0.y), c1 = __int_as_float(m1.y);
        float c2 = __int_as_float(m2.y), c3 = __int_as_float(m3.y);
        float c4 = __int_as_float(m4.y), c5 = __int_as_float(m5.y);
        float c6 = __int_as_float(m6.y), c7 = __int_as_float(m7.y);
        ACC8(v0, c0) ACC8(v1, c1) ACC8(v2, c2) ACC8(v3, c3)
        ACC8(v4, c4) ACC8(v5, c5) ACC8(v6, c6) ACC8(v7, c7)
    }
    for (; j + 7 < jend; j += 8) {
        int2 m0 = nme[j + half];
        int2 m1 = nme[j + 2 + half];
        int2 m2 = nme[j + 4 + half];
        int2 m3 = nme[j + 6 + half];
        uint4 v0 = *(const uint4*)(xy + m0.x * 256 + cl * 8);
        uint4 v1 = *(const uint4*)(xy + m1.x * 256 + cl * 8);
        uint4 v2 = *(const uint4*)(xy + m2.x * 256 + cl * 8);
        uint4 v3 = *(const uint4*)(xy + m3.x * 256 + cl * 8);
        float c0 = __int_as_float(m0.y), c1 = __int_as_float(m1.y);
        float c2 = __int_as_float(m2.y), c3 = __int_as_float(m3.y);
        ACC8(v0, c0) ACC8(v1, c1) ACC8(v2, c2) ACC8(v3, c3)
    }
    for (; j < jend; j += 2) {
        int idx = j + half;
        if (idx < jend) {
            int2 m = nme[idx];
            uint4 v = *(const uint4*)(xy + m.x * 256 + cl * 8);
            float cf = __int_as_float(m.y);
            ACC8(v, cf)
        }
    }

    aY0 += __shfl_xor(aY0, 32, 64); aY1 += __shfl_xor(aY1, 32, 64);
    aX0 += __shfl_xor(aX0, 32, 64); aX1 += __shfl_xor(aX1, 32, 64);
    aY2 += __shfl_xor(aY2, 32, 64); aY3 += __shfl_xor(aY3, 32, 64);
    aX2 += __shfl_xor(aX2, 32, 64); aX3 += __shfl_xor(aX3, 32, 64);
    if (half == 0) {
        float* zr = zp + (((p << 11) + i) << 8) + cl * 8;
        *(float4*)(zr) = make_float4(aY0, aY1, aX0, aX1);
        *(float4*)(zr + 4) = make_float4(aY2, aY3, aX2, aX3);
    }
}

// ---------------- reduce partials + fused output matvecs ----------------
__global__ __launch_bounds__(256) void k_reduce(const float* __restrict__ zp,
                                                const float* __restrict__ W2, const float* __restrict__ b2,
                                                const float* __restrict__ W3, const float* __restrict__ b3,
                                                float* __restrict__ out) {
    int i = blockIdx.x;   // node 0..2046
    int t = threadIdx.x;
    __shared__ float zm[128], zxm[128];
    float s = 0.f;
    #pragma unroll
    for (int p = 0; p < 8; ++p) s += zp[(((p << 11) + i) << 8) + t];
    s *= (1.0f / 64.0f);
    int k = t >> 2, r = t & 3;
    if (r < 2) zm[2 * k + r] = s; else zxm[2 * k + (r - 2)] = s;
    __syncthreads();
    int cc = t & 127;
    if (t < 128) {
        float acc = b2[cc];
        #pragma unroll 8
        for (int f = 0; f < 128; ++f) acc += zm[f] * W2[f * 128 + cc];
        out[i * 128 + cc] = acc;
    } else {
        float acc = b3[cc];
        #pragma unroll 8
        for (int f = 0; f < 128; ++f) acc += (zxm[f] - zm[f]) * W3[f * 128 + cc];
        out[2047 * 128 + i * 128 + cc] = acc;
    }
}

// ---------------- launch ----------------
// Workspace lifetimes: zp aliases {dis, degq01, degq23, gstartq} — all dead
// after k_A, before k_propx writes zp. pos_pn/invdeg/nme/xy live past that
// point and sit above the 16.8MB zp window.

extern "C" void kernel_launch(void* const* d_in, const int* in_sizes, int n_in,
                              void* d_out, int out_size, void* d_ws, size_t ws_size,
                              hipStream_t stream) {
    const float* x    = (const float*)d_in[0];
    const int* ei     = (const int*)d_in[1];
    const int* center = (const int*)d_in[3];
    const float* W1 = (const float*)d_in[4];
    const float* b1 = (const float*)d_in[5];
    const float* W2 = (const float*)d_in[6];
    const float* b2 = (const float*)d_in[7];
    const float* W3 = (const float*)d_in[8];
    const float* b3 = (const float*)d_in[9];
    const float* Wm = (const float*)d_in[10];
    const float* bm = (const float*)d_in[11];
    float* out = (float*)d_out;

    char* ws = (char*)d_ws;
    float*  dis     = (float*)(ws + 0);          // 512 KB   (dead after k_scatter)
    uint32* degq01  = (uint32*)(ws + 524288);    // 512 KB   (dead after k_A)
    uint32* degq23  = (uint32*)(ws + 1048576);   // 512 KB   (dead after k_A)
    int*    gstartq = (int*)(ws + 1572864);      // 2 MB     (dead after k_A)
    float*  zp      = (float*)(ws + 0);          // 16.8 MB  (aliases the 4 above; propx->reduce)
    int*    pos_pn  = (int*)(ws + 16777216);     // 66560 B reserve
    float*  invdeg  = (float*)(ws + 16843776);   // 512 KB
    float*  A       = (float*)(ws + 17368064);   // 32 KB
    u16*    Wtp     = (u16*)(ws + 17400832);     // 32 KB
    int2*   nme     = (int2*)(ws + 17433600);    // 8 MB
    u16*    xy      = (u16*)(ws + 25822208);     // 67 MB   (end ~92.9 MB)

    k_hist<<<dim3(Gg), dim3(1024), 0, stream>>>(ei, degq01, degq23, dis, invdeg);
    k_scan_p<<<dim3(8), dim3(1024), 0, stream>>>(degq01, degq23, pos_pn);
    k_start<<<dim3(Nn / 256), dim3(256), 0, stream>>>(degq01, degq23, pos_pn, gstartq);
    k_scatter<<<dim3(Gg), dim3(1024), 0, stream>>>(ei, dis, gstartq, nme);
    k_trans<<<dim3(64), dim3(256), 0, stream>>>(Wm, Wtp);
    k_A<<<dim3(Gg), dim3(128), 0, stream>>>(x, center, invdeg, gstartq, degq01, degq23, nme, W1, b1, Wm, bm, A);
    k_masky<<<dim3(2048), dim3(256), 0, stream>>>(x, Wtp, A, xy);
    k_propx<<<dim3(4096), dim3(256), 0, stream>>>(xy, invdeg, pos_pn, nme, zp);
    k_reduce<<<dim3(Nn - 1), dim3(256), 0, stream>>>(zp, W2, b2, W3, b3, out);
}